// Round 13
// baseline (138.008 us; speedup 1.0000x reference)
//
#include <hip/hip_runtime.h>

// Problem dims (fixed by reference)
#define T_TOTAL (32 * 4096)   // B*S = 131072 tokens
#define FDIM 256
#define NG 2                  // groups
#define NN 128                // entries per group
#define DDIM 128              // group dim
#define EDIM 256              // embed dim

#define TAU 0.004f            // bf16x3-vs-f32 safety margin for argmax gap
#define CAP 16384             // max flagged (t,g) entries (expected ~1k)

typedef __attribute__((ext_vector_type(4))) float f32x4;
typedef __attribute__((ext_vector_type(8))) short short8;

// ---------------------------------------------------------------------------
// Kernel P (prep): CO = codebooks @ W_out slices ; BT = split-bf16 W^T ;
// zero flag counter. One block per (g,n) = 256 blocks x 256 threads.
// ---------------------------------------------------------------------------
__global__ __launch_bounds__(256) void prep_kernel(
    const float* __restrict__ codebooks,  // [2][128][128]
    const float* __restrict__ W_out,      // [256][256]
    const float* __restrict__ Wl,         // [2][128 k][128 n]
    float* __restrict__ CO,               // [2][128][256]
    short* __restrict__ BT,               // [2 lev][2 g][128 n][128 k]
    int* __restrict__ flag_count)
{
    const int gn  = blockIdx.x;           // g*128 + n
    const int g   = gn >> 7;
    const int tid = threadIdx.x;
    __shared__ float cb[DDIM];
    if (tid < DDIM) cb[tid] = codebooks[gn * DDIM + tid];
    if (tid >= 128) {
        const int k = tid - 128;
        const int n = gn & 127;
        const float x = Wl[((size_t)g * DDIM + k) * NN + n];
        const unsigned u = __float_as_uint(x);
        const float hi = __uint_as_float(u & 0xffff0000u);
        const unsigned u2 = __float_as_uint(x - hi);   // exact residual
        BT[(size_t)g * 16384 + n * 128 + k] = (short)(u >> 16);
        BT[32768 + (size_t)g * 16384 + n * 128 + k] = (short)(u2 >> 16);
    }
    if (gn == 0 && tid == 0) *flag_count = 0;
    __syncthreads();
    float acc = 0.f;
    const float* wcol = W_out + (g * DDIM) * EDIM + tid;
#pragma unroll 4
    for (int d = 0; d < DDIM; ++d) acc += cb[d] * wcol[d * EDIM];
    CO[gn * EDIM + tid] = acc;
}

// ---------------------------------------------------------------------------
// Kernel M (main v13): r11 structure + T14 pipeline, with the prev-stage
// combine in the RACE-SAFE slot (between barrier-1 and barrier-2, as in r11;
// r12 put it after barrier-2 and raced with pm writes from compute).
// Per stage: split F(st) [in regs since st-1] -> barrier1 -> ds_write F-LDS
//   -> issue F(st+1) loads -> combine prev partials (tid<64) -> barrier2
//   -> issue G(st+1) loads -> 4 x 16-token MFMA subtiles (B from LDS, W regs)
// Block = 512 thr = 8 waves, ONE group, 256 tokens / 4 stages.
// ---------------------------------------------------------------------------
__global__ __launch_bounds__(512) void pq_v13_kernel(
    const float* __restrict__ features,   // [T][256]
    const float* __restrict__ gumbel,     // [T][2][128]
    const short* __restrict__ BT,         // [2 lev][2 g][128 n][128 k]
    const float* __restrict__ bl,         // [2][128]
    float* __restrict__ idx_f,            // [T][2] float-encoded indices
    int* __restrict__ flag_count,
    int* __restrict__ flag_list)
{
    __shared__ short8 Flds[2048];         // 32 KB: [lev][tok][chunk ^ (tok&7)]
    __shared__ float pm1s[8][64];
    __shared__ float pm2s[8][64];
    __shared__ int   pi1s[8][64];

    const int tid  = threadIdx.x;
    const int g    = blockIdx.x & 1;
    const int span = blockIdx.x >> 1;     // 0..511
    const int w    = tid >> 6;            // wave = n-tile 0..7
    const int l    = tid & 63;
    const int q    = l & 15;              // token col / A row
    const int h    = l >> 4;              // k-octet / D-subrow
    const int n0   = w * 16;
    const int tb0  = span * 256;

    // ---- persistent W fragments: lane (q,h) holds W[n0+q][ks*32+h*8..+7]
    const short* bt1 = BT + (size_t)g * 16384 + (n0 + q) * 128 + h * 8;
    short8 A1[4], A2[4];
#pragma unroll
    for (int ks = 0; ks < 4; ++ks) {
        A1[ks] = *reinterpret_cast<const short8*>(bt1 + ks * 32);
        A2[ks] = *reinterpret_cast<const short8*>(bt1 + 32768 + ks * 32);
    }
    const f32x4 bv = *reinterpret_cast<const f32x4*>(bl + g * NN + n0 + h * 4);

    // staging role: thread = (stok, skc)
    const int stok = tid >> 3;            // 0..63
    const int skc  = tid & 7;             // 0..7 (16-f32 chunks)
    const int swz  = stok & 7;

    const float* fstage = features + (size_t)(tb0 + stok) * FDIM + g * DDIM + skc * 16;
    const float* gq     = gumbel + ((size_t)(tb0 + q) * NG + g) * NN + n0 + h * 4;

    // pipeline registers
    f32x4 F[4];        // F-window for the *next* split (single buffer in time)
    f32x4 G[2][4];     // gumbel double buffer: [st&1][subtile]

    // ---- prologue: F(0), G(0)
#pragma unroll
    for (int j = 0; j < 4; ++j)
        F[j] = *reinterpret_cast<const f32x4*>(fstage + j * 4);
#pragma unroll
    for (int s = 0; s < 4; ++s)
        G[0][s] = *reinterpret_cast<const f32x4*>(gq + (size_t)(s * 16) * NG * NN);

#pragma unroll
    for (int st = 0; st < 4; ++st) {
        const int cur = st & 1;
        const int nxt = cur ^ 1;

        // ---- split F(st) (loaded one stage ago) to two bf16 planes
        short8 SH0, SH1, SL0, SL1;
#pragma unroll
        for (int e = 0; e < 4; ++e) {
            unsigned u; float hi;
            u = __float_as_uint(F[0][e]); hi = __uint_as_float(u & 0xffff0000u);
            SH0[e]     = (short)(u >> 16); SL0[e]     = (short)(__float_as_uint(F[0][e] - hi) >> 16);
            u = __float_as_uint(F[1][e]); hi = __uint_as_float(u & 0xffff0000u);
            SH0[4 + e] = (short)(u >> 16); SL0[4 + e] = (short)(__float_as_uint(F[1][e] - hi) >> 16);
            u = __float_as_uint(F[2][e]); hi = __uint_as_float(u & 0xffff0000u);
            SH1[e]     = (short)(u >> 16); SL1[e]     = (short)(__float_as_uint(F[2][e] - hi) >> 16);
            u = __float_as_uint(F[3][e]); hi = __uint_as_float(u & 0xffff0000u);
            SH1[4 + e] = (short)(u >> 16); SL1[4 + e] = (short)(__float_as_uint(F[3][e] - hi) >> 16);
        }

        __syncthreads();   // barrier-1: prev compute done (Flds reads + pm writes)

        // ---- ds_write the two planes, swizzled (proven r11 layout)
        {
            short8* rowHi = Flds + stok * 16;
            short8* rowLo = Flds + 1024 + stok * 16;
            rowHi[(2 * skc)     ^ swz] = SH0;
            rowHi[(2 * skc + 1) ^ swz] = SH1;
            rowLo[(2 * skc)     ^ swz] = SL0;
            rowLo[(2 * skc + 1) ^ swz] = SL1;
        }

        // ---- issue F(st+1) loads: consumed at next stage's split
        if (st < 3) {
            const float* fp = fstage + (size_t)(st + 1) * 64 * FDIM;
#pragma unroll
            for (int j = 0; j < 4; ++j)
                F[j] = *reinterpret_cast<const f32x4*>(fp + j * 4);
        }

        // ---- combine prev stage's partials (RACE-SAFE: before barrier-2,
        //      so no overlap with this stage's pm writes in compute)
        if (st > 0 && tid < 64) {
            float c1 = pm1s[0][tid], c2 = pm2s[0][tid];
            int   ci = pi1s[0][tid];
#pragma unroll
            for (int p = 1; p < 8; ++p) {
                const float a1 = pm1s[p][tid];
                const float a2 = pm2s[p][tid];
                const int   ai = pi1s[p][tid];
                if (a1 > c1)      { c2 = fmaxf(c1, a2); c1 = a1; ci = ai; }
                else if (a1 < c1) { c2 = fmaxf(c2, a1); }
                else              { c2 = c1; ci = min(ci, ai); }
            }
            const int t = tb0 + (st - 1) * 64 + tid;
            idx_f[(size_t)t * NG + g] = (float)ci;
            if (c1 - c2 < TAU) {
                const int p = atomicAdd(flag_count, 1);
                if (p < CAP) flag_list[p] = t * NG + g;
            }
        }

        __syncthreads();   // barrier-2: staging visible, combine reads done

        // ---- issue G(st+1) loads: consumed at next stage's epilogues
        if (st < 3) {
            const float* gp = gq + (size_t)(st + 1) * 64 * NG * NN;
#pragma unroll
            for (int s = 0; s < 4; ++s)
                G[nxt][s] = *reinterpret_cast<const f32x4*>(gp + (size_t)(s * 16) * NG * NN);
        }

        // ---- compute: 4 subtiles of 16 tokens (B from LDS, W in regs)
#pragma unroll
        for (int s = 0; s < 4; ++s) {
            const int rbase = (s * 16 + q) * 16;
            f32x4 acc = (f32x4){0.f, 0.f, 0.f, 0.f};
#pragma unroll
            for (int ks = 0; ks < 4; ++ks) {
                const int ci0 = (ks * 4 + h) ^ (q & 7);
                const short8 B1 = Flds[rbase + ci0];
                const short8 B2 = Flds[1024 + rbase + ci0];
                acc = __builtin_amdgcn_mfma_f32_16x16x32_bf16(A1[ks], B1, acc, 0, 0, 0);
                acc = __builtin_amdgcn_mfma_f32_16x16x32_bf16(A2[ks], B1, acc, 0, 0, 0);
                acc = __builtin_amdgcn_mfma_f32_16x16x32_bf16(A1[ks], B2, acc, 0, 0, 0);
            }

            // per-lane top-2 over its 4 n-values (gumbel from prefetched regs)
            float m1 = -3.4e38f, m2 = -3.4e38f;
            int   i1 = 0;
#pragma unroll
            for (int r = 0; r < 4; ++r) {
                const float vv = acc[r] + bv[r] + G[cur][s][r];
                const int   n  = n0 + h * 4 + r;
                if (vv > m1) { m2 = m1; m1 = vv; i1 = n; }
                else         { m2 = fmaxf(m2, vv); }
            }
            // combine the 4 h-lanes sharing this token
#pragma unroll
            for (int off = 16; off < 64; off <<= 1) {
                const float om1 = __shfl_xor(m1, off);
                const int   oi1 = __shfl_xor(i1, off);
                const float om2 = __shfl_xor(m2, off);
                if (om1 > m1)      { m2 = fmaxf(m1, om2); m1 = om1; i1 = oi1; }
                else if (om1 < m1) { m2 = fmaxf(m2, om1); }
                else               { m2 = m1; i1 = min(i1, oi1); }
            }
            if (h == 0) {
                pm1s[w][s * 16 + q] = m1;
                pm2s[w][s * 16 + q] = m2;
                pi1s[w][s * 16 + q] = i1;
            }
        }
    }

    // ---- final combine for stage 3
    __syncthreads();
    if (tid < 64) {
        float c1 = pm1s[0][tid], c2 = pm2s[0][tid];
        int   ci = pi1s[0][tid];
#pragma unroll
        for (int p = 1; p < 8; ++p) {
            const float a1 = pm1s[p][tid];
            const float a2 = pm2s[p][tid];
            const int   ai = pi1s[p][tid];
            if (a1 > c1)      { c2 = fmaxf(c1, a2); c1 = a1; ci = ai; }
            else if (a1 < c1) { c2 = fmaxf(c2, a1); }
            else              { c2 = c1; ci = min(ci, ai); }
        }
        const int t = tb0 + 3 * 64 + tid;
        idx_f[(size_t)t * NG + g] = (float)ci;
        if (c1 - c2 < TAU) {
            const int p = atomicAdd(flag_count, 1);
            if (p < CAP) flag_list[p] = t * NG + g;
        }
    }
}

// ---------------------------------------------------------------------------
// Kernel F (fixup): exact sequential-f32 fmaf recompute for flagged (t,g).
// ---------------------------------------------------------------------------
__global__ __launch_bounds__(128) void fixup_kernel(
    const float* __restrict__ features,
    const float* __restrict__ gumbel,
    const float* __restrict__ Wl,         // [2][128 k][128 n]
    const float* __restrict__ bl,
    float* __restrict__ idx_f,
    const int* __restrict__ flag_count,
    const int* __restrict__ flag_list)
{
    __shared__ float sm[2];
    __shared__ int   si[2];
    int total = *flag_count;
    if (total > CAP) total = CAP;
    const int n = threadIdx.x;

    for (int e = blockIdx.x; e < total; e += gridDim.x) {
        const int code = flag_list[e];
        const int t = code >> 1, g = code & 1;
        const float* fpr = features + (size_t)t * FDIM + g * DDIM;
        const float* wp  = Wl + (size_t)g * DDIM * NN + n;
        float dot = 0.f;
#pragma unroll 8
        for (int k = 0; k < DDIM; ++k) dot = fmaf(fpr[k], wp[(size_t)k * NN], dot);
        const float v = (dot + bl[g * NN + n]) + gumbel[((size_t)t * NG + g) * NN + n];

        float m = v; int bi = n;
#pragma unroll
        for (int off = 1; off < 64; off <<= 1) {
            const float om = __shfl_xor(m, off);
            const int   ob = __shfl_xor(bi, off);
            if (om > m || (om == m && ob < bi)) { m = om; bi = ob; }
        }
        if ((n & 63) == 0) { sm[n >> 6] = m; si[n >> 6] = bi; }
        __syncthreads();
        if (n == 0) {
            const float mA = sm[0], mB = sm[1];
            const int bA = si[0], bB = si[1];
            const int best = (mB > mA || (mB == mA && bB < bA)) ? bB : bA;
            idx_f[code] = (float)best;
        }
        __syncthreads();
    }
}

// ---------------------------------------------------------------------------
// Kernel C: out[t][e] = CO[0][i0][e] + CO[1][i1][e] + b_out[e]
// ---------------------------------------------------------------------------
__global__ __launch_bounds__(256) void out_kernel(
    const float* __restrict__ CO,      // [2][128][256]
    const float* __restrict__ b_out,   // [256]
    const float* __restrict__ idx_f,   // [T][2] float-encoded
    float* __restrict__ out)           // [T][256]
{
    const int tid = threadIdx.x;
    const int e4  = tid & 63;    // float4 index in e
    const int ts  = tid >> 6;    // 0..3
    const int tbase = blockIdx.x * 16;
    const float4 b = *reinterpret_cast<const float4*>(b_out + e4 * 4);

#pragma unroll
    for (int it = 0; it < 4; ++it) {
        const int t  = tbase + it * 4 + ts;
        const int i0 = (int)idx_f[t * NG + 0];
        const int i1 = (int)idx_f[t * NG + 1];
        const float4 c0 = *reinterpret_cast<const float4*>(CO + (size_t)i0 * EDIM + e4 * 4);
        const float4 c1 = *reinterpret_cast<const float4*>(CO + (size_t)(NN + i1) * EDIM + e4 * 4);
        float4 o;
        o.x = c0.x + c1.x + b.x;
        o.y = c0.y + c1.y + b.y;
        o.z = c0.z + c1.z + b.z;
        o.w = c0.w + c1.w + b.w;
        *reinterpret_cast<float4*>(out + (size_t)t * EDIM + e4 * 4) = o;
    }
}

// ---------------------------------------------------------------------------
extern "C" void kernel_launch(void* const* d_in, const int* in_sizes, int n_in,
                              void* d_out, int out_size, void* d_ws, size_t ws_size,
                              hipStream_t stream) {
    const float* features  = (const float*)d_in[0];  // [32,4096,256]
    const float* gumbel    = (const float*)d_in[1];  // [32,4096,2,128]
    const float* Wl        = (const float*)d_in[2];  // [2,128,128]
    const float* bl        = (const float*)d_in[3];  // [2,128]
    const float* codebooks = (const float*)d_in[4];  // [2,128,128]
    const float* W_out     = (const float*)d_in[5];  // [256,256]
    const float* b_out     = (const float*)d_in[6];  // [256]

    float* out   = (float*)d_out;                    // [T,256]
    float* idx_f = out + (size_t)T_TOTAL * EDIM;     // [T,2] float-encoded indices

    // ws layout: CO (256KB) | BT (128KB) | flag_count (pad 256B) | flag_list (64KB)
    char* ws = (char*)d_ws;
    float* CO         = (float*)ws;                        // 262144 B
    short* BT         = (short*)(ws + 262144);             // 131072 B
    int*   flag_count = (int*)(ws + 262144 + 131072);      // @393216
    int*   flag_list  = (int*)(ws + 393216 + 256);         // @393472, 64KB

    prep_kernel<<<NG * NN, 256, 0, stream>>>(codebooks, W_out, Wl, CO, BT, flag_count);
    pq_v13_kernel<<<1024, 512, 0, stream>>>(
        features, gumbel, BT, bl, idx_f, flag_count, flag_list);
    fixup_kernel<<<1024, 128, 0, stream>>>(
        features, gumbel, Wl, bl, idx_f, flag_count, flag_list);
    out_kernel<<<T_TOTAL / 16, 256, 0, stream>>>(CO, b_out, idx_f, out);
}

// Round 14
// 132.202 us; speedup vs baseline: 1.0439x; 1.0439x over previous
//
#include <hip/hip_runtime.h>

// Problem dims (fixed by reference)
#define T_TOTAL (32 * 4096)   // B*S = 131072 tokens
#define FDIM 256
#define NG 2                  // groups
#define NN 128                // entries per group
#define DDIM 128              // group dim
#define EDIM 256              // embed dim

#define TAU 0.004f            // bf16x3-vs-f32 safety margin for argmax gap
#define CAP 16384             // max flagged (t,g) entries (expected ~1k)

typedef __attribute__((ext_vector_type(4))) float f32x4;
typedef __attribute__((ext_vector_type(8))) short short8;

// ---------------------------------------------------------------------------
// Kernel P (prep): CO = codebooks @ W_out slices ; BT = split-bf16 W^T ;
// zero flag counter. One block per (g,n) = 256 blocks x 256 threads.
// ---------------------------------------------------------------------------
__global__ __launch_bounds__(256) void prep_kernel(
    const float* __restrict__ codebooks,  // [2][128][128]
    const float* __restrict__ W_out,      // [256][256]
    const float* __restrict__ Wl,         // [2][128 k][128 n]
    float* __restrict__ CO,               // [2][128][256]
    short* __restrict__ BT,               // [2 lev][2 g][128 n][128 k]
    int* __restrict__ flag_count)
{
    const int gn  = blockIdx.x;           // g*128 + n
    const int g   = gn >> 7;
    const int tid = threadIdx.x;
    __shared__ float cb[DDIM];
    if (tid < DDIM) cb[tid] = codebooks[gn * DDIM + tid];
    if (tid >= 128) {
        const int k = tid - 128;
        const int n = gn & 127;
        const float x = Wl[((size_t)g * DDIM + k) * NN + n];
        const unsigned u = __float_as_uint(x);
        const float hi = __uint_as_float(u & 0xffff0000u);
        const unsigned u2 = __float_as_uint(x - hi);   // exact residual
        BT[(size_t)g * 16384 + n * 128 + k] = (short)(u >> 16);
        BT[32768 + (size_t)g * 16384 + n * 128 + k] = (short)(u2 >> 16);
    }
    if (gn == 0 && tid == 0) *flag_count = 0;
    __syncthreads();
    float acc = 0.f;
    const float* wcol = W_out + (g * DDIM) * EDIM + tid;
#pragma unroll 4
    for (int d = 0; d < DDIM; ++d) acc += cb[d] * wcol[d * EDIM];
    CO[gn * EDIM + tid] = acc;
}

// ---------------------------------------------------------------------------
// Kernel M (main v15): r11 structure with loads issued at COMPUTE-WINDOW
// START (right after barrier-2). Rationale: hipcc drains vmcnt(0) at every
// __syncthreads, so loads issued near a barrier are fully exposed (r11/r13).
// Issued after barrier-2 they have the whole compute phase to land.
// Per stage: split F(st)[regs, loaded last stage] -> barrier-1 -> ds_write
//   -> combine(st-1) [race-safe slot] -> barrier-2
//   -> issue F(st+1) + G(st) -> 4 x 16-token MFMA subtiles.
// Block = 512 thr = 8 waves (wave = 16-n tile), ONE group, 256 tokens/4 stages.
// W fragments persistent in regs (32 VGPR); numerics identical to r5-r13.
// ---------------------------------------------------------------------------
__global__ __launch_bounds__(512) void pq_v15_kernel(
    const float* __restrict__ features,   // [T][256]
    const float* __restrict__ gumbel,     // [T][2][128]
    const short* __restrict__ BT,         // [2 lev][2 g][128 n][128 k]
    const float* __restrict__ bl,         // [2][128]
    float* __restrict__ idx_f,            // [T][2] float-encoded indices
    int* __restrict__ flag_count,
    int* __restrict__ flag_list)
{
    __shared__ short8 Flds[2048];         // 32 KB: [lev][tok][chunk ^ (tok&7)]
    __shared__ float pm1s[8][64];
    __shared__ float pm2s[8][64];
    __shared__ int   pi1s[8][64];

    const int tid  = threadIdx.x;
    const int g    = blockIdx.x & 1;
    const int span = blockIdx.x >> 1;     // 0..511
    const int w    = tid >> 6;            // wave = n-tile 0..7
    const int l    = tid & 63;
    const int q    = l & 15;              // token col / A row
    const int h    = l >> 4;              // k-octet / D-subrow
    const int n0   = w * 16;
    const int tb0  = span * 256;

    // ---- persistent W fragments: lane (q,h) holds W[n0+q][ks*32+h*8..+7]
    const short* bt1 = BT + (size_t)g * 16384 + (n0 + q) * 128 + h * 8;
    short8 A1[4], A2[4];
#pragma unroll
    for (int ks = 0; ks < 4; ++ks) {
        A1[ks] = *reinterpret_cast<const short8*>(bt1 + ks * 32);
        A2[ks] = *reinterpret_cast<const short8*>(bt1 + 32768 + ks * 32);
    }
    const f32x4 bv = *reinterpret_cast<const f32x4*>(bl + g * NN + n0 + h * 4);

    // staging role: thread = (stok, skc)
    const int stok = tid >> 3;            // 0..63
    const int skc  = tid & 7;             // 0..7 (16-f32 chunks)
    const int swz  = stok & 7;

    const float* fstage = features + (size_t)(tb0 + stok) * FDIM + g * DDIM + skc * 16;
    const float* gq     = gumbel + ((size_t)(tb0 + q) * NG + g) * NN + n0 + h * 4;

    // pipeline registers (all statically indexed under full unroll)
    f32x4 F[4];        // features for the NEXT split (loaded one stage ahead)
    f32x4 G[4];        // this stage's gumbel, issued at compute-window start

    // ---- prologue: F(0)
#pragma unroll
    for (int j = 0; j < 4; ++j)
        F[j] = *reinterpret_cast<const f32x4*>(fstage + j * 4);

#pragma unroll
    for (int st = 0; st < 4; ++st) {
        // ---- split F(st) (loaded one stage ago) to two bf16 planes
        short8 SH0, SH1, SL0, SL1;
#pragma unroll
        for (int e = 0; e < 4; ++e) {
            unsigned u; float hi;
            u = __float_as_uint(F[0][e]); hi = __uint_as_float(u & 0xffff0000u);
            SH0[e]     = (short)(u >> 16); SL0[e]     = (short)(__float_as_uint(F[0][e] - hi) >> 16);
            u = __float_as_uint(F[1][e]); hi = __uint_as_float(u & 0xffff0000u);
            SH0[4 + e] = (short)(u >> 16); SL0[4 + e] = (short)(__float_as_uint(F[1][e] - hi) >> 16);
            u = __float_as_uint(F[2][e]); hi = __uint_as_float(u & 0xffff0000u);
            SH1[e]     = (short)(u >> 16); SL1[e]     = (short)(__float_as_uint(F[2][e] - hi) >> 16);
            u = __float_as_uint(F[3][e]); hi = __uint_as_float(u & 0xffff0000u);
            SH1[4 + e] = (short)(u >> 16); SL1[4 + e] = (short)(__float_as_uint(F[3][e] - hi) >> 16);
        }

        __syncthreads();   // barrier-1: prev compute done (Flds reads + pm writes)

        // ---- ds_write the two planes, swizzled (proven r11 layout)
        {
            short8* rowHi = Flds + stok * 16;
            short8* rowLo = Flds + 1024 + stok * 16;
            rowHi[(2 * skc)     ^ swz] = SH0;
            rowHi[(2 * skc + 1) ^ swz] = SH1;
            rowLo[(2 * skc)     ^ swz] = SL0;
            rowLo[(2 * skc + 1) ^ swz] = SL1;
        }

        // ---- combine prev stage's partials (race-safe slot: between barriers)
        if (st > 0 && tid < 64) {
            float c1 = pm1s[0][tid], c2 = pm2s[0][tid];
            int   ci = pi1s[0][tid];
#pragma unroll
            for (int p = 1; p < 8; ++p) {
                const float a1 = pm1s[p][tid];
                const float a2 = pm2s[p][tid];
                const int   ai = pi1s[p][tid];
                if (a1 > c1)      { c2 = fmaxf(c1, a2); c1 = a1; ci = ai; }
                else if (a1 < c1) { c2 = fmaxf(c2, a1); }
                else              { c2 = c1; ci = min(ci, ai); }
            }
            const int t = tb0 + (st - 1) * 64 + tid;
            idx_f[(size_t)t * NG + g] = (float)ci;
            if (c1 - c2 < TAU) {
                const int p = atomicAdd(flag_count, 1);
                if (p < CAP) flag_list[p] = t * NG + g;
            }
        }

        __syncthreads();   // barrier-2: staging visible, combine reads done

        // ---- COMPUTE-WINDOW START: issue all global loads now.
        // F(st+1): consumed at next stage's split (~full compute phase away;
        // the vmcnt drain at next barrier-1 is then nearly free).
        if (st < 3) {
            const float* fp = fstage + (size_t)(st + 1) * 64 * FDIM;
#pragma unroll
            for (int j = 0; j < 4; ++j)
                F[j] = *reinterpret_cast<const f32x4*>(fp + j * 4);
        }
        // G(st): consumed at the 4 subtile epilogues (300-1500 cy after issue).
#pragma unroll
        for (int s = 0; s < 4; ++s)
            G[s] = *reinterpret_cast<const f32x4*>(
                gq + (size_t)(st * 64 + s * 16) * NG * NN);

        // ---- compute: 4 subtiles of 16 tokens (B from LDS, W in regs)
#pragma unroll
        for (int s = 0; s < 4; ++s) {
            const int rbase = (s * 16 + q) * 16;
            f32x4 acc = (f32x4){0.f, 0.f, 0.f, 0.f};
#pragma unroll
            for (int ks = 0; ks < 4; ++ks) {
                const int ci0 = (ks * 4 + h) ^ (q & 7);
                const short8 B1 = Flds[rbase + ci0];
                const short8 B2 = Flds[1024 + rbase + ci0];
                acc = __builtin_amdgcn_mfma_f32_16x16x32_bf16(A1[ks], B1, acc, 0, 0, 0);
                acc = __builtin_amdgcn_mfma_f32_16x16x32_bf16(A2[ks], B1, acc, 0, 0, 0);
                acc = __builtin_amdgcn_mfma_f32_16x16x32_bf16(A1[ks], B2, acc, 0, 0, 0);
            }

            // per-lane top-2 over its 4 n-values (gumbel from prefetched regs)
            float m1 = -3.4e38f, m2 = -3.4e38f;
            int   i1 = 0;
#pragma unroll
            for (int r = 0; r < 4; ++r) {
                const float vv = acc[r] + bv[r] + G[s][r];
                const int   n  = n0 + h * 4 + r;
                if (vv > m1) { m2 = m1; m1 = vv; i1 = n; }
                else         { m2 = fmaxf(m2, vv); }
            }
            // combine the 4 h-lanes sharing this token
#pragma unroll
            for (int off = 16; off < 64; off <<= 1) {
                const float om1 = __shfl_xor(m1, off);
                const int   oi1 = __shfl_xor(i1, off);
                const float om2 = __shfl_xor(m2, off);
                if (om1 > m1)      { m2 = fmaxf(m1, om2); m1 = om1; i1 = oi1; }
                else if (om1 < m1) { m2 = fmaxf(m2, om1); }
                else               { m2 = m1; i1 = min(i1, oi1); }
            }
            if (h == 0) {
                pm1s[w][s * 16 + q] = m1;
                pm2s[w][s * 16 + q] = m2;
                pi1s[w][s * 16 + q] = i1;
            }
        }
    }

    // ---- final combine for stage 3
    __syncthreads();
    if (tid < 64) {
        float c1 = pm1s[0][tid], c2 = pm2s[0][tid];
        int   ci = pi1s[0][tid];
#pragma unroll
        for (int p = 1; p < 8; ++p) {
            const float a1 = pm1s[p][tid];
            const float a2 = pm2s[p][tid];
            const int   ai = pi1s[p][tid];
            if (a1 > c1)      { c2 = fmaxf(c1, a2); c1 = a1; ci = ai; }
            else if (a1 < c1) { c2 = fmaxf(c2, a1); }
            else              { c2 = c1; ci = min(ci, ai); }
        }
        const int t = tb0 + 3 * 64 + tid;
        idx_f[(size_t)t * NG + g] = (float)ci;
        if (c1 - c2 < TAU) {
            const int p = atomicAdd(flag_count, 1);
            if (p < CAP) flag_list[p] = t * NG + g;
        }
    }
}

// ---------------------------------------------------------------------------
// Kernel F (fixup): exact sequential-f32 fmaf recompute for flagged (t,g).
// ---------------------------------------------------------------------------
__global__ __launch_bounds__(128) void fixup_kernel(
    const float* __restrict__ features,
    const float* __restrict__ gumbel,
    const float* __restrict__ Wl,         // [2][128 k][128 n]
    const float* __restrict__ bl,
    float* __restrict__ idx_f,
    const int* __restrict__ flag_count,
    const int* __restrict__ flag_list)
{
    __shared__ float sm[2];
    __shared__ int   si[2];
    int total = *flag_count;
    if (total > CAP) total = CAP;
    const int n = threadIdx.x;

    for (int e = blockIdx.x; e < total; e += gridDim.x) {
        const int code = flag_list[e];
        const int t = code >> 1, g = code & 1;
        const float* fpr = features + (size_t)t * FDIM + g * DDIM;
        const float* wp  = Wl + (size_t)g * DDIM * NN + n;
        float dot = 0.f;
#pragma unroll 8
        for (int k = 0; k < DDIM; ++k) dot = fmaf(fpr[k], wp[(size_t)k * NN], dot);
        const float v = (dot + bl[g * NN + n]) + gumbel[((size_t)t * NG + g) * NN + n];

        float m = v; int bi = n;
#pragma unroll
        for (int off = 1; off < 64; off <<= 1) {
            const float om = __shfl_xor(m, off);
            const int   ob = __shfl_xor(bi, off);
            if (om > m || (om == m && ob < bi)) { m = om; bi = ob; }
        }
        if ((n & 63) == 0) { sm[n >> 6] = m; si[n >> 6] = bi; }
        __syncthreads();
        if (n == 0) {
            const float mA = sm[0], mB = sm[1];
            const int bA = si[0], bB = si[1];
            const int best = (mB > mA || (mB == mA && bB < bA)) ? bB : bA;
            idx_f[code] = (float)best;
        }
        __syncthreads();
    }
}

// ---------------------------------------------------------------------------
// Kernel C: out[t][e] = CO[0][i0][e] + CO[1][i1][e] + b_out[e]
// ---------------------------------------------------------------------------
__global__ __launch_bounds__(256) void out_kernel(
    const float* __restrict__ CO,      // [2][128][256]
    const float* __restrict__ b_out,   // [256]
    const float* __restrict__ idx_f,   // [T][2] float-encoded
    float* __restrict__ out)           // [T][256]
{
    const int tid = threadIdx.x;
    const int e4  = tid & 63;    // float4 index in e
    const int ts  = tid >> 6;    // 0..3
    const int tbase = blockIdx.x * 16;
    const float4 b = *reinterpret_cast<const float4*>(b_out + e4 * 4);

#pragma unroll
    for (int it = 0; it < 4; ++it) {
        const int t  = tbase + it * 4 + ts;
        const int i0 = (int)idx_f[t * NG + 0];
        const int i1 = (int)idx_f[t * NG + 1];
        const float4 c0 = *reinterpret_cast<const float4*>(CO + (size_t)i0 * EDIM + e4 * 4);
        const float4 c1 = *reinterpret_cast<const float4*>(CO + (size_t)(NN + i1) * EDIM + e4 * 4);
        float4 o;
        o.x = c0.x + c1.x + b.x;
        o.y = c0.y + c1.y + b.y;
        o.z = c0.z + c1.z + b.z;
        o.w = c0.w + c1.w + b.w;
        *reinterpret_cast<float4*>(out + (size_t)t * EDIM + e4 * 4) = o;
    }
}

// ---------------------------------------------------------------------------
extern "C" void kernel_launch(void* const* d_in, const int* in_sizes, int n_in,
                              void* d_out, int out_size, void* d_ws, size_t ws_size,
                              hipStream_t stream) {
    const float* features  = (const float*)d_in[0];  // [32,4096,256]
    const float* gumbel    = (const float*)d_in[1];  // [32,4096,2,128]
    const float* Wl        = (const float*)d_in[2];  // [2,128,128]
    const float* bl        = (const float*)d_in[3];  // [2,128]
    const float* codebooks = (const float*)d_in[4];  // [2,128,128]
    const float* W_out     = (const float*)d_in[5];  // [256,256]
    const float* b_out     = (const float*)d_in[6];  // [256]

    float* out   = (float*)d_out;                    // [T,256]
    float* idx_f = out + (size_t)T_TOTAL * EDIM;     // [T,2] float-encoded indices

    // ws layout: CO (256KB) | BT (128KB) | flag_count (pad 256B) | flag_list (64KB)
    char* ws = (char*)d_ws;
    float* CO         = (float*)ws;                        // 262144 B
    short* BT         = (short*)(ws + 262144);             // 131072 B
    int*   flag_count = (int*)(ws + 262144 + 131072);      // @393216
    int*   flag_list  = (int*)(ws + 393216 + 256);         // @393472, 64KB

    prep_kernel<<<NG * NN, 256, 0, stream>>>(codebooks, W_out, Wl, CO, BT, flag_count);
    pq_v15_kernel<<<1024, 512, 0, stream>>>(
        features, gumbel, BT, bl, idx_f, flag_count, flag_list);
    fixup_kernel<<<1024, 128, 0, stream>>>(
        features, gumbel, Wl, bl, idx_f, flag_count, flag_list);
    out_kernel<<<T_TOTAL / 16, 256, 0, stream>>>(CO, b_out, idx_f, out);
}

// Round 15
// 118.722 us; speedup vs baseline: 1.1624x; 1.1135x over previous
//
#include <hip/hip_runtime.h>

// Problem dims (fixed by reference)
#define T_TOTAL (32 * 4096)   // B*S = 131072 tokens
#define FDIM 256
#define NG 2                  // groups
#define NN 128                // entries per group
#define DDIM 128              // group dim
#define EDIM 256              // embed dim

#define TAU 0.004f            // bf16x3-vs-f32 safety margin for argmax gap
#define CAP 16384             // max flagged (t,g) entries (expected ~1k)

typedef __attribute__((ext_vector_type(4))) float f32x4;
typedef __attribute__((ext_vector_type(8))) short short8;

// ---------------------------------------------------------------------------
// Kernel P (prep): CO = codebooks @ W_out slices ; BT = split-bf16 W^T ;
// zero flag counter. One block per (g,n) = 256 blocks x 256 threads.
// ---------------------------------------------------------------------------
__global__ __launch_bounds__(256) void prep_kernel(
    const float* __restrict__ codebooks,  // [2][128][128]
    const float* __restrict__ W_out,      // [256][256]
    const float* __restrict__ Wl,         // [2][128 k][128 n]
    float* __restrict__ CO,               // [2][128][256]
    short* __restrict__ BT,               // [2 lev][2 g][128 n][128 k]
    int* __restrict__ flag_count)
{
    const int gn  = blockIdx.x;           // g*128 + n
    const int g   = gn >> 7;
    const int tid = threadIdx.x;
    __shared__ float cb[DDIM];
    if (tid < DDIM) cb[tid] = codebooks[gn * DDIM + tid];
    if (tid >= 128) {
        const int k = tid - 128;
        const int n = gn & 127;
        const float x = Wl[((size_t)g * DDIM + k) * NN + n];
        const unsigned u = __float_as_uint(x);
        const float hi = __uint_as_float(u & 0xffff0000u);
        const unsigned u2 = __float_as_uint(x - hi);   // exact residual
        BT[(size_t)g * 16384 + n * 128 + k] = (short)(u >> 16);
        BT[32768 + (size_t)g * 16384 + n * 128 + k] = (short)(u2 >> 16);
    }
    if (gn == 0 && tid == 0) *flag_count = 0;
    __syncthreads();
    float acc = 0.f;
    const float* wcol = W_out + (g * DDIM) * EDIM + tid;
#pragma unroll 4
    for (int d = 0; d < DDIM; ++d) acc += cb[d] * wcol[d * EDIM];
    CO[gn * EDIM + tid] = acc;
}

// ---------------------------------------------------------------------------
// Kernel M (main v16): r8 structure (W both split levels in 64 KB LDS,
// barrier-free main loop, 8 waves x 16 tokens x 128 n) with ASM-PINNED
// global loads. Plain-C prefetch gets sunk by the compiler (r5/r8/r11/r14:
// VGPR 52-108, loads at uses, ~900cy HBM stalls serial). Volatile-asm
// global_load_dwordx4 cannot be moved; manual s_waitcnt vmcnt(0) +
// sched_barrier(0) (rule #18) places the single wait where latency is
// already hidden:
//   [vmcnt(0)] split F(it) -> issue GA(it) -> MFMA (LDS-only, ~2.5k cy)
//   -> [vmcnt(0)] -> issue F(it+1) -> epilogue (GA consumed, F in flight)
// Bias in LDS to keep pinned set (F32+GA32+acc32) under the 128-VGPR cliff.
// Block = 512 thr = 8 waves, ONE group, 512 tokens over 4 iterations.
// Numerics byte-identical to rounds 5-14 (same split, TAU, fixup).
// ---------------------------------------------------------------------------
__global__ __launch_bounds__(512) void pq_v16_kernel(
    const float* __restrict__ features,   // [T][256]
    const float* __restrict__ gumbel,     // [T][2][128]
    const short* __restrict__ BT,         // [2 lev][2 g][128 n][128 k]
    const float* __restrict__ bl,         // [2][128]
    float* __restrict__ idx_f,            // [T][2] float-encoded indices
    int* __restrict__ flag_count,
    int* __restrict__ flag_list)
{
    __shared__ short8 Wlds[4096];   // 64 KB: [lev][n][slot ^ (n&15)]
    __shared__ float  bl_s[NN];

    const int tid = threadIdx.x;
    const int g   = blockIdx.x & 1;
    const int gb  = blockIdx.x >> 1;    // 0..255
    const int w   = tid >> 6;           // wave 0..7
    const int l   = tid & 63;
    const int q   = l & 15;             // token slot / A row low bits
    const int h   = l >> 4;             // k-chunk selector / n-subrow

    // ---- stage W (both levels) for this group into LDS, swizzled (r8)
    {
        const short8* src = reinterpret_cast<const short8*>(BT) + g * 2048;
#pragma unroll
        for (int i = 0; i < 8; ++i) {
            const int S   = tid + i * 512;       // 0..4095
            const int lev = S >> 11;
            const int n   = (S >> 4) & 127;
            const int sl  = S & 15;
            Wlds[lev * 2048 + n * 16 + (sl ^ (n & 15))] = src[lev * 4096 + n * 16 + sl];
        }
        if (tid < NN) bl_s[tid] = bl[g * NN + tid];
    }
    __syncthreads();

    const int t0 = gb * 512 + w * 16 + q;    // lane's token at it=0 (+128/iter)
    const float* fbase = features + (size_t)t0 * FDIM + g * DDIM + h * 8;
    const float* gbase = gumbel + ((size_t)t0 * NG + g) * NN + h * 4;

    f32x4 F[8], GA[8];

#define GLOAD(dst, ptr) \
    asm volatile("global_load_dwordx4 %0, %1, off" : "=v"(dst) : "v"(ptr))
#define VWAIT() do { \
    asm volatile("s_waitcnt vmcnt(0)" ::: "memory"); \
    __builtin_amdgcn_sched_barrier(0); } while (0)

    // ---- prologue: issue F(0)
#pragma unroll
    for (int j = 0; j < 8; ++j)
        GLOAD(F[j], fbase + (j >> 1) * 32 + (j & 1) * 4);

#define PQ_IT(IT)                                                               \
    {                                                                           \
        VWAIT();   /* F(IT) landed (was in flight across prev epilogue) */      \
        /* issue GA(IT): consumed after the MFMA phase */                       \
        {                                                                       \
            const float* gp = gbase + (size_t)(IT) * 128 * NG * NN;             \
            _Pragma("unroll")                                                   \
            for (int nt = 0; nt < 8; ++nt)                                      \
                GLOAD(GA[nt], gp + nt * 16);                                    \
        }                                                                       \
        f32x4 acc[8];                                                           \
        _Pragma("unroll")                                                       \
        for (int nt = 0; nt < 8; ++nt) acc[nt] = (f32x4){0.f, 0.f, 0.f, 0.f};   \
        _Pragma("unroll")                                                       \
        for (int ks = 0; ks < 4; ++ks) {                                        \
            short8 B1, B2;                                                      \
            _Pragma("unroll")                                                   \
            for (int e = 0; e < 4; ++e) {                                       \
                const unsigned ua = __float_as_uint(F[2 * ks][e]);              \
                const float ha = __uint_as_float(ua & 0xffff0000u);             \
                const unsigned ra = __float_as_uint(F[2 * ks][e] - ha);         \
                B1[e] = (short)(ua >> 16);                                      \
                B2[e] = (short)(ra >> 16);                                      \
                const unsigned ub = __float_as_uint(F[2 * ks + 1][e]);          \
                const float hb = __uint_as_float(ub & 0xffff0000u);             \
                const unsigned rb = __float_as_uint(F[2 * ks + 1][e] - hb);     \
                B1[4 + e] = (short)(ub >> 16);                                  \
                B2[4 + e] = (short)(rb >> 16);                                  \
            }                                                                   \
            _Pragma("unroll")                                                   \
            for (int nt = 0; nt < 8; ++nt) {                                    \
                const int base = (nt * 16 + q) * 16 + ((ks * 4 + h) ^ q);       \
                const short8 A1 = Wlds[base];                                   \
                const short8 A2 = Wlds[2048 + base];                            \
                acc[nt] = __builtin_amdgcn_mfma_f32_16x16x32_bf16(A1, B1, acc[nt], 0, 0, 0); \
                acc[nt] = __builtin_amdgcn_mfma_f32_16x16x32_bf16(A2, B1, acc[nt], 0, 0, 0); \
                acc[nt] = __builtin_amdgcn_mfma_f32_16x16x32_bf16(A1, B2, acc[nt], 0, 0, 0); \
            }                                                                   \
        }                                                                       \
        VWAIT();   /* GA(IT) landed (was in flight across the MFMA phase) */    \
        /* issue F(IT+1): in flight across the epilogue below */                \
        if ((IT) < 3) {                                                         \
            const float* fp = fbase + (size_t)((IT) + 1) * 128 * FDIM;          \
            _Pragma("unroll")                                                   \
            for (int j = 0; j < 8; ++j)                                         \
                GLOAD(F[j], fp + (j >> 1) * 32 + (j & 1) * 4);                  \
        }                                                                       \
        /* epilogue: +bias(LDS) +gumbel(regs), top-2 argmax */                  \
        float m1 = -3.4e38f, m2 = -3.4e38f;                                     \
        int   i1 = 0;                                                           \
        _Pragma("unroll")                                                       \
        for (int nt = 0; nt < 8; ++nt) {                                        \
            const f32x4 bvr = *reinterpret_cast<const f32x4*>(&bl_s[nt * 16 + h * 4]); \
            _Pragma("unroll")                                                   \
            for (int r = 0; r < 4; ++r) {                                       \
                const float vv = acc[nt][r] + bvr[r] + GA[nt][r];               \
                const int   n  = nt * 16 + h * 4 + r;                           \
                if (vv > m1) { m2 = m1; m1 = vv; i1 = n; }                      \
                else         { m2 = fmaxf(m2, vv); }                            \
            }                                                                   \
        }                                                                       \
        _Pragma("unroll")                                                       \
        for (int off = 16; off < 64; off <<= 1) {                               \
            const float om1 = __shfl_xor(m1, off);                              \
            const int   oi1 = __shfl_xor(i1, off);                              \
            const float om2 = __shfl_xor(m2, off);                              \
            if (om1 > m1)      { m2 = fmaxf(m1, om2); m1 = om1; i1 = oi1; }     \
            else if (om1 < m1) { m2 = fmaxf(m2, om1); }                         \
            else               { m2 = m1; i1 = min(i1, oi1); }                  \
        }                                                                       \
        if (h == 0) {                                                           \
            const int t = t0 + (IT) * 128;                                      \
            idx_f[(size_t)t * NG + g] = (float)i1;                              \
            if (m1 - m2 < TAU) {                                                \
                const int p = atomicAdd(flag_count, 1);                         \
                if (p < CAP) flag_list[p] = t * NG + g;                         \
            }                                                                   \
        }                                                                       \
    }

    PQ_IT(0)
    PQ_IT(1)
    PQ_IT(2)
    PQ_IT(3)
#undef PQ_IT
#undef GLOAD
#undef VWAIT
}

// ---------------------------------------------------------------------------
// Kernel F (fixup): exact sequential-f32 fmaf recompute for flagged (t,g).
// ---------------------------------------------------------------------------
__global__ __launch_bounds__(128) void fixup_kernel(
    const float* __restrict__ features,
    const float* __restrict__ gumbel,
    const float* __restrict__ Wl,         // [2][128 k][128 n]
    const float* __restrict__ bl,
    float* __restrict__ idx_f,
    const int* __restrict__ flag_count,
    const int* __restrict__ flag_list)
{
    __shared__ float sm[2];
    __shared__ int   si[2];
    int total = *flag_count;
    if (total > CAP) total = CAP;
    const int n = threadIdx.x;

    for (int e = blockIdx.x; e < total; e += gridDim.x) {
        const int code = flag_list[e];
        const int t = code >> 1, g = code & 1;
        const float* fpr = features + (size_t)t * FDIM + g * DDIM;
        const float* wp  = Wl + (size_t)g * DDIM * NN + n;
        float dot = 0.f;
#pragma unroll 8
        for (int k = 0; k < DDIM; ++k) dot = fmaf(fpr[k], wp[(size_t)k * NN], dot);
        const float v = (dot + bl[g * NN + n]) + gumbel[((size_t)t * NG + g) * NN + n];

        float m = v; int bi = n;
#pragma unroll
        for (int off = 1; off < 64; off <<= 1) {
            const float om = __shfl_xor(m, off);
            const int   ob = __shfl_xor(bi, off);
            if (om > m || (om == m && ob < bi)) { m = om; bi = ob; }
        }
        if ((n & 63) == 0) { sm[n >> 6] = m; si[n >> 6] = bi; }
        __syncthreads();
        if (n == 0) {
            const float mA = sm[0], mB = sm[1];
            const int bA = si[0], bB = si[1];
            const int best = (mB > mA || (mB == mA && bB < bA)) ? bB : bA;
            idx_f[code] = (float)best;
        }
        __syncthreads();
    }
}

// ---------------------------------------------------------------------------
// Kernel C: out[t][e] = CO[0][i0][e] + CO[1][i1][e] + b_out[e]
// ---------------------------------------------------------------------------
__global__ __launch_bounds__(256) void out_kernel(
    const float* __restrict__ CO,      // [2][128][256]
    const float* __restrict__ b_out,   // [256]
    const float* __restrict__ idx_f,   // [T][2] float-encoded
    float* __restrict__ out)           // [T][256]
{
    const int tid = threadIdx.x;
    const int e4  = tid & 63;    // float4 index in e
    const int ts  = tid >> 6;    // 0..3
    const int tbase = blockIdx.x * 16;
    const float4 b = *reinterpret_cast<const float4*>(b_out + e4 * 4);

#pragma unroll
    for (int it = 0; it < 4; ++it) {
        const int t  = tbase + it * 4 + ts;
        const int i0 = (int)idx_f[t * NG + 0];
        const int i1 = (int)idx_f[t * NG + 1];
        const float4 c0 = *reinterpret_cast<const float4*>(CO + (size_t)i0 * EDIM + e4 * 4);
        const float4 c1 = *reinterpret_cast<const float4*>(CO + (size_t)(NN + i1) * EDIM + e4 * 4);
        float4 o;
        o.x = c0.x + c1.x + b.x;
        o.y = c0.y + c1.y + b.y;
        o.z = c0.z + c1.z + b.z;
        o.w = c0.w + c1.w + b.w;
        *reinterpret_cast<float4*>(out + (size_t)t * EDIM + e4 * 4) = o;
    }
}

// ---------------------------------------------------------------------------
extern "C" void kernel_launch(void* const* d_in, const int* in_sizes, int n_in,
                              void* d_out, int out_size, void* d_ws, size_t ws_size,
                              hipStream_t stream) {
    const float* features  = (const float*)d_in[0];  // [32,4096,256]
    const float* gumbel    = (const float*)d_in[1];  // [32,4096,2,128]
    const float* Wl        = (const float*)d_in[2];  // [2,128,128]
    const float* bl        = (const float*)d_in[3];  // [2,128]
    const float* codebooks = (const float*)d_in[4];  // [2,128,128]
    const float* W_out     = (const float*)d_in[5];  // [256,256]
    const float* b_out     = (const float*)d_in[6];  // [256]

    float* out   = (float*)d_out;                    // [T,256]
    float* idx_f = out + (size_t)T_TOTAL * EDIM;     // [T,2] float-encoded indices

    // ws layout: CO (256KB) | BT (128KB) | flag_count (pad 256B) | flag_list (64KB)
    char* ws = (char*)d_ws;
    float* CO         = (float*)ws;                        // 262144 B
    short* BT         = (short*)(ws + 262144);             // 131072 B
    int*   flag_count = (int*)(ws + 262144 + 131072);      // @393216
    int*   flag_list  = (int*)(ws + 393216 + 256);         // @393472, 64KB

    prep_kernel<<<NG * NN, 256, 0, stream>>>(codebooks, W_out, Wl, CO, BT, flag_count);
    pq_v16_kernel<<<512, 512, 0, stream>>>(
        features, gumbel, BT, bl, idx_f, flag_count, flag_list);
    fixup_kernel<<<1024, 128, 0, stream>>>(
        features, gumbel, Wl, bl, idx_f, flag_count, flag_list);
    out_kernel<<<T_TOTAL / 16, 256, 0, stream>>>(CO, b_out, idx_f, out);
}